// Round 14
// baseline (1442.556 us; speedup 1.0000x reference)
//
#include <hip/hip_runtime.h>

// Fused windowed multi-head attention for MI355X (gfx950).
// B=8192 windows, N=49 tokens, C=192, H=6 heads, HD=32.
// Inputs/outputs are FP32 (per reference); mask int32. Interior compute bf16 MFMA.
//
// Structure (v13): PERSISTENT blocks, 1024 x 384 threads (6 waves = 6 heads),
// WPB=8 windows per block, with ASYNC global->LDS staging
// (__builtin_amdgcn_global_load_lds): zero registers held across phases (the
// v6/v11 spill failure is structurally impossible), x for window i+1 streams
// into LDS while window i computes. Double-buffered fp32 x tile AND bf16 O
// tile -> ONE barrier per window (hazard analysis in comments below).
//
// x LDS layout: fp32 [64][192] per buffer, XOR-swizzled at 16B granularity:
//   physical_byte = logical_byte ^ ((row&7)<<4)      (involution; row = u/768
//   is preserved since the XOR only touches bits 4-6). global_load_lds writes
//   LDS linearly (wave base + lane*16), so the staging PRE-SWIZZLES the
//   global source address per lane (m173 pattern); reads apply the same XOR.
//   Rows >=49 stage clamped-but-garbage data: finite, and neutralized by the
//   key mask / never-stored q rows (verified v12).
//
// Per-window (numerics identical to v10, bit-exact canonical absmax):
//   [issue async stage of x(i+1)+mask(i+1) -> buffers c^1]
//   phase 2: merged QKV GEMM; af = 2 swizzled f32x4 LDS reads + cvt8 (same
//            RNE values as the old staged path). q,k swapped mfma(W,X);
//            v normal. Collapse: qf/kf NATURAL xpose (bit-exact S), vf
//            dual-packed registers.
//   phase 4+5 per q-tile: S=mfma32(kf,qf); masked softmax (2 shfl_xor);
//            pf=cvt8; O=mfma32(pf,vf) -> ob[c].
//   [wpj fragment preload]
//   __syncthreads()   // ONLY barrier: drains async stage (had a whole
//                     // window to fly), publishes ob[c], seals xbuf[c^1]
//   phase 6: projection GEMM from ob[c] + bias, fp32 stores (drain under
//            next window's compute; no end barrier needed: ob double-buffered,
//            next conflicting ob[c] write is 2 iterations away, behind the
//            next iteration's collective barrier).
//
// Why: v12 proved the kernel is latency-bound (global-direct x reads:
// -49%, utilizations dropped proportionally); v5 proved lockstep TLP is null;
// v6/v11 proved register prefetch spills. Async LDS staging is the only
// remaining spill-free overlap lever: deletes stage instructions, stage
// latency exposure, store drain, and 7/8 of dispatch overhead per window.
//
// Weights repacked each call fp32 -> bf16 in B-fragment-contiguous layout:
// wp[(kt*COLS + col)*32 + kk] = w[(kt*32+kk)*COLS + col].

typedef __attribute__((ext_vector_type(8))) short short8;
typedef __attribute__((ext_vector_type(4))) float f32x4;

#define SCALE 0.17677669529663687f   // 32^-0.5
#define WPB   8                      // windows per block

__device__ __forceinline__ unsigned short f2bf(float x) {
    union { float f; unsigned int i; } v; v.f = x;
    return (unsigned short)((v.i + 0x7FFFu + ((v.i >> 16) & 1u)) >> 16);
}

// packed f32x2 -> bf16x2 (RNE), 1 instr
__device__ __forceinline__ unsigned int pkbf(float lo, float hi) {
    unsigned int r;
    asm("v_cvt_pk_bf16_f32 %0, %1, %2" : "=v"(r) : "v"(lo), "v"(hi));
    return r;
}

// 8 f32 (two f32x4) -> bf16x8 fragment word (natural element order)
__device__ __forceinline__ short8 cvt8(f32x4 lo, f32x4 hi) {
    union { short8 s; unsigned int u[4]; } r;
    r.u[0] = pkbf(lo[0], lo[1]);
    r.u[1] = pkbf(lo[2], lo[3]);
    r.u[2] = pkbf(hi[0], hi[1]);
    r.u[3] = pkbf(hi[2], hi[3]);
    return r.s;
}

__device__ __forceinline__ f32x4 addb(f32x4 v, float b) {
    v[0] += b; v[1] += b; v[2] += b; v[3] += b;
    return v;
}

// C-layout pair (two 16-row tiles) -> NATURAL-order A/B MFMA fragment.
// dst lane (quad,l16) elem e from src lane ((quad&1)*2+(e>>2))*16+l16,
// tile selected by quad>>1.
__device__ __forceinline__ short8 xpose(f32x4 tlo, f32x4 thi, int srcA, bool hi) {
    unsigned int pl0 = pkbf(tlo[0], tlo[1]);
    unsigned int pl1 = pkbf(tlo[2], tlo[3]);
    unsigned int ph0 = pkbf(thi[0], thi[1]);
    unsigned int ph1 = pkbf(thi[2], thi[3]);
    unsigned int a0 = (unsigned int)__shfl((int)pl0, srcA);
    unsigned int b0 = (unsigned int)__shfl((int)ph0, srcA);
    unsigned int a1 = (unsigned int)__shfl((int)pl1, srcA);
    unsigned int b1 = (unsigned int)__shfl((int)ph1, srcA);
    unsigned int a2 = (unsigned int)__shfl((int)pl0, srcA + 16);
    unsigned int b2 = (unsigned int)__shfl((int)ph0, srcA + 16);
    unsigned int a3 = (unsigned int)__shfl((int)pl1, srcA + 16);
    unsigned int b3 = (unsigned int)__shfl((int)ph1, srcA + 16);
    union { short8 s8; unsigned int u[4]; } f;
    f.u[0] = hi ? b0 : a0;
    f.u[1] = hi ? b1 : a1;
    f.u[2] = hi ? b2 : a2;
    f.u[3] = hi ? b3 : a3;
    return f.s8;
}

__global__ void repack_kernel(const float* __restrict__ wqkv,
                              const float* __restrict__ wproj,
                              unsigned short* __restrict__ wq_pack,
                              unsigned short* __restrict__ wp_pack) {
    int idx = blockIdx.x * 256 + threadIdx.x;
    if (idx < 6 * 576 * 32) {
        int kk  = idx & 31;
        int col = (idx >> 5) % 576;
        int kt  = idx / (576 * 32);
        wq_pack[idx] = f2bf(wqkv[(kt * 32 + kk) * 576 + col]);
    } else {
        int j = idx - 6 * 576 * 32;
        if (j < 6 * 192 * 32) {
            int kk  = j & 31;
            int col = (j >> 5) % 192;
            int kt  = j / (192 * 32);
            wp_pack[j] = f2bf(wproj[(kt * 32 + kk) * 192 + col]);
        }
    }
}

__global__ __launch_bounds__(384)
void win_attn_kernel(const float* __restrict__ x,
                     const int* __restrict__ mask,
                     const float* __restrict__ bqkv,
                     const float* __restrict__ bproj,
                     const unsigned short* __restrict__ wq,
                     const unsigned short* __restrict__ wpj,
                     float* __restrict__ out) {
    // xbf: fp32 x tile [64 rows][192 floats], XOR-swizzled, double-buffered.
    // ob : bf16 O tile [64][200], double-buffered.  mbuf: raw mask ints.
    __shared__ __align__(16) float          xbf[2][12288];
    __shared__ __align__(16) unsigned short ob[2][12800];
    __shared__                int           mbuf[2][64];

    const int tid  = threadIdx.x;
    const int lane = tid & 63;
    const int h    = tid >> 6;      // wave index == head
    const int quad = lane >> 4;
    const int l16  = lane & 15;
    const int b0   = blockIdx.x * WPB;

    const int  srcA   = ((lane & 16) << 1) | l16;  // ((quad&1)*2)*16 + l16
    const bool hiq    = (lane & 32) != 0;          // quad>>1
    const int  mask_l = (l16 & 7) << 4;            // read-side swizzle mask

    int colb[6];
    #pragma unroll
    for (int t = 0; t < 6; ++t) colb[t] = (t >> 1) * 192 + h * 32 + (t & 1) * 16;

    // async stage of one window's x (+ mask) into buffer nb. No VGPRs held:
    // global_load_lds writes LDS directly. LDS dest is wave-uniform base +
    // lane*16; the global source is per-lane PRE-SWIZZLED so that the linear
    // LDS image equals the swizzled layout the readers expect.
    auto stage_async = [&](int nb, int bwin) {
        const char* xs = (const char*)(x + (size_t)bwin * 9408);
        #pragma unroll
        for (int j = 0; j < 8; ++j) {
            int s   = j * 384 + h * 64 + lane;   // 16B slot 0..3071
            int row = s / 48;                    // 48 slots per 768B row
            int cb  = (s - row * 48) * 16;       // physical byte within row
            int lcb = cb ^ ((row & 7) << 4);     // logical byte (involution)
            int rs  = row < 49 ? row : 0;        // clamp: stay in-bounds
            const void* g = (const void*)(xs + rs * 768 + lcb);
            void* l = (void*)((char*)&xbf[nb][0] + (size_t)(j * 384 + h * 64) * 16);
            __builtin_amdgcn_global_load_lds(
                (const __attribute__((address_space(1))) void*)g,
                (__attribute__((address_space(3))) void*)l, 16, 0, 0);
        }
        if (h == 0) {
            int ml = lane < 49 ? lane : 48;
            const void* gm = (const void*)(mask + bwin * 49 + ml);
            void* lm = (void*)&mbuf[nb][0];
            __builtin_amdgcn_global_load_lds(
                (const __attribute__((address_space(1))) void*)gm,
                (__attribute__((address_space(3))) void*)lm, 4, 0, 0);
        }
    };

    // ---------------- prologue: stage window b0 -> buffers 0 --------------
    stage_async(0, b0);
    __syncthreads();

    #pragma unroll 1
    for (int wi = 0; wi < WPB; ++wi) {
        const int c = wi & 1;
        const int b = b0 + wi;

        // issue next window's async stage (flies under this window's compute;
        // xbf[c^1] is free: its last reads were sealed by the previous
        // iteration's barrier)
        if (wi + 1 < WPB) stage_async(c ^ 1, b + 1);

        const char* xcur = (const char*)&xbf[c][0];

        // ---------------- phase 2: merged QKV GEMM ------------------------
        // t=0..3 (q,k) swapped: acc[t][nt] = Y[token=nt*16+l16][colb[t]+quad*4+r]
        // t=4..5 (v) normal:    acc[t][mt] = V[token=mt*16+quad*4+r][..+l16]
        f32x4 acc[6][4];
        #pragma unroll
        for (int t = 0; t < 6; ++t)
            #pragma unroll
            for (int mt = 0; mt < 4; ++mt)
                acc[t][mt] = (f32x4){0.f, 0.f, 0.f, 0.f};

        #pragma unroll
        for (int kt = 0; kt < 6; ++kt) {
            short8 af[4];
            #pragma unroll
            for (int mt = 0; mt < 4; ++mt) {
                int ub = (mt * 16 + l16) * 768 + kt * 128 + quad * 32;
                f32x4 lo = *(const f32x4*)(const void*)(xcur + (ub ^ mask_l));
                f32x4 hi = *(const f32x4*)(const void*)(xcur + ((ub + 16) ^ mask_l));
                af[mt] = cvt8(lo, hi);   // same RNE as staged path: bit-exact
            }
            #pragma unroll
            for (int t = 0; t < 6; ++t) {
                short8 bw = *(const short8*)(const void*)
                            &wq[(size_t)(kt * 576 + colb[t] + l16) * 32 + quad * 8];
                #pragma unroll
                for (int mt = 0; mt < 4; ++mt) {
                    if (t < 4)
                        acc[t][mt] = __builtin_amdgcn_mfma_f32_16x16x32_bf16(
                                         bw, af[mt], acc[t][mt], 0, 0, 0);
                    else
                        acc[t][mt] = __builtin_amdgcn_mfma_f32_16x16x32_bf16(
                                         af[mt], bw, acc[t][mt], 0, 0, 0);
                }
            }
        }

        // bias + collapse: qf/kf NATURAL order (bit-exact S), vf dual-packed.
        short8 qf[4], kf[4], vf[2][2];
        {
            f32x4 bq0 = *(const f32x4*)(const void*)&bqkv[colb[0] + quad * 4];
            f32x4 bq1 = *(const f32x4*)(const void*)&bqkv[colb[1] + quad * 4];
            f32x4 bk0 = *(const f32x4*)(const void*)&bqkv[colb[2] + quad * 4];
            f32x4 bk1 = *(const f32x4*)(const void*)&bqkv[colb[3] + quad * 4];
            #pragma unroll
            for (int nt = 0; nt < 4; ++nt) {
                qf[nt] = xpose(acc[0][nt] + bq0, acc[1][nt] + bq1, srcA, hiq);
                kf[nt] = xpose(acc[2][nt] + bk0, acc[3][nt] + bk1, srcA, hiq);
            }
            float bv0 = bqkv[colb[4] + l16];
            float bv1 = bqkv[colb[5] + l16];
            #pragma unroll
            for (int j = 0; j < 2; ++j) {
                vf[0][j] = cvt8(addb(acc[4][2 * j], bv0),
                                addb(acc[4][2 * j + 1], bv0));
                vf[1][j] = cvt8(addb(acc[5][2 * j], bv1),
                                addb(acc[5][2 * j + 1], bv1));
            }
        }

        // mask bias per lane from LDS ints (broadcast reads, conflict-free)
        f32x4 mb4[4];
        #pragma unroll
        for (int mt = 0; mt < 4; ++mt)
            #pragma unroll
            for (int r = 0; r < 4; ++r) {
                int row = mt * 16 + quad * 4 + r;
                mb4[mt][r] = (row < 49 && mbuf[c][row] != 0) ? 0.0f : -1e30f;
            }

        // ---------------- phase 4+5: per q-tile S, softmax, O -------------
        unsigned short* obb = &ob[c][0];
        #pragma unroll
        for (int nt = 0; nt < 4; ++nt) {
            f32x4 sr[4];
            #pragma unroll
            for (int mt = 0; mt < 4; ++mt) {
                sr[mt] = (f32x4){0.f, 0.f, 0.f, 0.f};
                sr[mt] = __builtin_amdgcn_mfma_f32_16x16x32_bf16(
                             kf[mt], qf[nt], sr[mt], 0, 0, 0);
            }
            float pm[4];
            #pragma unroll
            for (int mt = 0; mt < 4; ++mt) {
                #pragma unroll
                for (int r = 0; r < 4; ++r)
                    sr[mt][r] = sr[mt][r] * SCALE + mb4[mt][r];
                pm[mt] = fmaxf(fmaxf(sr[mt][0], sr[mt][1]),
                               fmaxf(sr[mt][2], sr[mt][3]));
            }
            float mx = fmaxf(fmaxf(pm[0], pm[1]), fmaxf(pm[2], pm[3]));
            mx = fmaxf(mx, __shfl_xor(mx, 16));
            mx = fmaxf(mx, __shfl_xor(mx, 32));
            float ps[4];
            #pragma unroll
            for (int mt = 0; mt < 4; ++mt) {
                #pragma unroll
                for (int r = 0; r < 4; ++r)
                    sr[mt][r] = __expf(sr[mt][r] - mx);
                ps[mt] = (sr[mt][0] + sr[mt][1]) + (sr[mt][2] + sr[mt][3]);
            }
            float sum = (ps[0] + ps[1]) + (ps[2] + ps[3]);
            sum += __shfl_xor(sum, 16);
            sum += __shfl_xor(sum, 32);
            float inv = 1.0f / sum;
            #pragma unroll
            for (int mt = 0; mt < 4; ++mt)
                #pragma unroll
                for (int r = 0; r < 4; ++r)
                    sr[mt][r] *= inv;

            short8 pf[2];
            pf[0] = cvt8(sr[0], sr[1]);
            pf[1] = cvt8(sr[2], sr[3]);

            f32x4 on[2];
            #pragma unroll
            for (int t = 0; t < 2; ++t)
                on[t] = (f32x4){0.f, 0.f, 0.f, 0.f};
            #pragma unroll
            for (int j = 0; j < 2; ++j)
                #pragma unroll
                for (int t = 0; t < 2; ++t)
                    on[t] = __builtin_amdgcn_mfma_f32_16x16x32_bf16(
                                pf[j], vf[t][j], on[t], 0, 0, 0);

            #pragma unroll
            for (int t = 0; t < 2; ++t)
                #pragma unroll
                for (int r = 0; r < 4; ++r)
                    obb[(nt * 16 + quad * 4 + r) * 200 + h * 32 + t * 16 + l16]
                        = f2bf(on[t][r]);
        }

        // preload projection-weight fragments (L2 latency under barrier)
        short8 bwp[6][2];
        #pragma unroll
        for (int kt = 0; kt < 6; ++kt)
            #pragma unroll
            for (int nt = 0; nt < 2; ++nt)
                bwp[kt][nt] = *(const short8*)(const void*)
                              &wpj[(size_t)(kt * 192 + h * 32 + nt * 16 + l16) * 32
                                   + quad * 8];

        __syncthreads();   // THE barrier: drains async stage; publishes ob[c];
                           // seals xbf[c^1] + mbuf[c^1] for next iteration

        // ---------------- phase 6: projection GEMM + bias + store ---------
        f32x4 po[2][4];
        #pragma unroll
        for (int nt = 0; nt < 2; ++nt)
            #pragma unroll
            for (int mt = 0; mt < 4; ++mt)
                po[nt][mt] = (f32x4){0.f, 0.f, 0.f, 0.f};

        #pragma unroll
        for (int kt = 0; kt < 6; ++kt) {
            short8 ao[4];
            #pragma unroll
            for (int mt = 0; mt < 4; ++mt)
                ao[mt] = *(const short8*)(const void*)
                         &obb[(mt * 16 + l16) * 200 + kt * 32 + quad * 8];
            #pragma unroll
            for (int nt = 0; nt < 2; ++nt)
                #pragma unroll
                for (int mt = 0; mt < 4; ++mt)
                    po[nt][mt] = __builtin_amdgcn_mfma_f32_16x16x32_bf16(
                                     ao[mt], bwp[kt][nt], po[nt][mt], 0, 0, 0);
        }

        #pragma unroll
        for (int nt = 0; nt < 2; ++nt) {
            int col = h * 32 + nt * 16 + l16;
            float bv = bproj[col];
            #pragma unroll
            for (int mt = 0; mt < 4; ++mt)
                #pragma unroll
                for (int r = 0; r < 4; ++r) {
                    int row = mt * 16 + quad * 4 + r;
                    if (row < 49)
                        out[(size_t)b * 9408 + row * 192 + col]
                            = po[nt][mt][r] + bv;
                }
        }
        // no end barrier: ob is double-buffered; the next conflicting ob[c]
        // write is 2 iterations away, behind the next collective barrier.
        // Stores drain under the next window's compute.
    }
}

extern "C" void kernel_launch(void* const* d_in, const int* in_sizes, int n_in,
                              void* d_out, int out_size, void* d_ws, size_t ws_size,
                              hipStream_t stream) {
    const float* x      = (const float*)d_in[0];
    const int*   mask   = (const int*)d_in[1];
    const float* w_qkv  = (const float*)d_in[2];
    const float* b_qkv  = (const float*)d_in[3];
    const float* w_proj = (const float*)d_in[4];
    const float* b_proj = (const float*)d_in[5];
    float*       out    = (float*)d_out;

    unsigned short* wq_pack = (unsigned short*)d_ws;          // 110592 elems
    unsigned short* wp_pack = wq_pack + 110592;               //  36864 elems

    repack_kernel<<<(110592 + 36864 + 255) / 256, 256, 0, stream>>>(
        w_qkv, w_proj, wq_pack, wp_pack);
    win_attn_kernel<<<8192 / WPB, 384, 0, stream>>>(x, mask, b_qkv, b_proj,
                                                    wq_pack, wp_pack, out);
}

// Round 15
// 825.051 us; speedup vs baseline: 1.7484x; 1.7484x over previous
//
#include <hip/hip_runtime.h>

// Fused windowed multi-head attention for MI355X (gfx950).
// B=8192 windows, N=49 tokens, C=192, H=6 heads, HD=32.
// Inputs/outputs are FP32 (per reference); mask int32. Interior compute bf16 MFMA.
//
// Structure (v14): 1 block per window, 768 threads = 12 waves. Wave (h,m)
// (h = head, m = token-half) owns token rows m*32..m*32+31 of head h.
// PER-WAVE CHAIN HALVED vs v10 (acc 96->48 regs, 144->72 QKV MFMAs, 8->4
// xposes, 4->2 softmax tiles, proj 48->24 MFMAs) with 2x the waves.
//
// Rationale: all 13 rounds fit one model -- per-window wall time tracks the
// per-wave dependency chain. v5 (2x waves, SAME chain) = null; v9/v10 chain
// cuts = proportional wins; v12 chain lengthening = proportional loss; and
// persistent pipelining spills (v6/v11/v13, 3 strikes, closed). v14 is the
// untested point: chains/2 at waves x2.
//
// Cross-wave K/V sharing: wave (h,m) stores its kf fragment words and
// dual-packed vf words VERBATIM (per-lane short8) to kfb[h][nt][lane] /
// vfb[h][t][j][lane]; the partner wave reads them back bit-identically
// (identical lane structure) -> zero layout math. All values, accumulation
// orders and conversions are bit-identical to v10 -> absmax must be exactly
// 4.882812e-4.
//
// Phases: 1 stage x (768 thr) + mask; B1; 2 QKV (half-M) + collapse + kf/vf
// publish; B2 (x dead -> O overlays x region); 4+5 per own q-tile: S (full K
// from kfb), softmax, PV (vf from vfb) -> O region; wpj preload; B3;
// 6 projection (own rows x own head cols) + bias + store.
//
// Weights repacked each call fp32 -> bf16 in B-fragment-contiguous layout:
// wp[(kt*COLS + col)*32 + kk] = w[(kt*32+kk)*COLS + col].

typedef __attribute__((ext_vector_type(8))) short short8;
typedef __attribute__((ext_vector_type(4))) float f32x4;

#define SCALE 0.17677669529663687f   // 32^-0.5

__device__ __forceinline__ unsigned short f2bf(float x) {
    union { float f; unsigned int i; } v; v.f = x;
    return (unsigned short)((v.i + 0x7FFFu + ((v.i >> 16) & 1u)) >> 16);
}

// packed f32x2 -> bf16x2 (RNE), 1 instr
__device__ __forceinline__ unsigned int pkbf(float lo, float hi) {
    unsigned int r;
    asm("v_cvt_pk_bf16_f32 %0, %1, %2" : "=v"(r) : "v"(lo), "v"(hi));
    return r;
}

// two C-layout f32x4 sub-tiles -> one dual-packed K=32 bf16 fragment
__device__ __forceinline__ short8 cvt8(f32x4 lo, f32x4 hi) {
    union { short8 s; unsigned int u[4]; } r;
    r.u[0] = pkbf(lo[0], lo[1]);
    r.u[1] = pkbf(lo[2], lo[3]);
    r.u[2] = pkbf(hi[0], hi[1]);
    r.u[3] = pkbf(hi[2], hi[3]);
    return r.s;
}

__device__ __forceinline__ f32x4 addb(f32x4 v, float b) {
    v[0] += b; v[1] += b; v[2] += b; v[3] += b;
    return v;
}

// C-layout pair (two 16-row tiles) -> NATURAL-order A/B MFMA fragment.
// dst lane (quad,l16) elem e from src lane ((quad&1)*2+(e>>2))*16+l16,
// tile selected by quad>>1.
__device__ __forceinline__ short8 xpose(f32x4 tlo, f32x4 thi, int srcA, bool hi) {
    unsigned int pl0 = pkbf(tlo[0], tlo[1]);
    unsigned int pl1 = pkbf(tlo[2], tlo[3]);
    unsigned int ph0 = pkbf(thi[0], thi[1]);
    unsigned int ph1 = pkbf(thi[2], thi[3]);
    unsigned int a0 = (unsigned int)__shfl((int)pl0, srcA);
    unsigned int b0 = (unsigned int)__shfl((int)ph0, srcA);
    unsigned int a1 = (unsigned int)__shfl((int)pl1, srcA);
    unsigned int b1 = (unsigned int)__shfl((int)ph1, srcA);
    unsigned int a2 = (unsigned int)__shfl((int)pl0, srcA + 16);
    unsigned int b2 = (unsigned int)__shfl((int)ph0, srcA + 16);
    unsigned int a3 = (unsigned int)__shfl((int)pl1, srcA + 16);
    unsigned int b3 = (unsigned int)__shfl((int)ph1, srcA + 16);
    union { short8 s8; unsigned int u[4]; } f;
    f.u[0] = hi ? b0 : a0;
    f.u[1] = hi ? b1 : a1;
    f.u[2] = hi ? b2 : a2;
    f.u[3] = hi ? b3 : a3;
    return f.s8;
}

__global__ void repack_kernel(const float* __restrict__ wqkv,
                              const float* __restrict__ wproj,
                              unsigned short* __restrict__ wq_pack,
                              unsigned short* __restrict__ wp_pack) {
    int idx = blockIdx.x * 256 + threadIdx.x;
    if (idx < 6 * 576 * 32) {
        int kk  = idx & 31;
        int col = (idx >> 5) % 576;
        int kt  = idx / (576 * 32);
        wq_pack[idx] = f2bf(wqkv[(kt * 32 + kk) * 576 + col]);
    } else {
        int j = idx - 6 * 576 * 32;
        if (j < 6 * 192 * 32) {
            int kk  = j & 31;
            int col = (j >> 5) % 192;
            int kt  = j / (192 * 32);
            wp_pack[j] = f2bf(wproj[(kt * 32 + kk) * 192 + col]);
        }
    }
}

__global__ __launch_bounds__(768)
void win_attn_kernel(const float* __restrict__ x,
                     const int* __restrict__ mask,
                     const float* __restrict__ bqkv,
                     const float* __restrict__ bproj,
                     const unsigned short* __restrict__ wq,
                     const unsigned short* __restrict__ wpj,
                     float* __restrict__ out) {
    // region: x tile 64x200 bf16 (phases 1-2), then O_all 64x200 (phases 5-6)
    //         -- x is dead block-wide after barrier 2, O written after it.
    // kfb   : verbatim per-lane kf fragment words, [head][token-tile][lane]
    // vfb   : verbatim per-lane dual-packed vf words, [head][dt][j][lane]
    __shared__ __align__(16) unsigned short region[12800];
    __shared__ __align__(16) short8 kfb[6][4][64];
    __shared__ __align__(16) short8 vfb[6][2][2][64];
    __shared__ __align__(16) float mbias[64];

    const int b    = blockIdx.x;
    const int tid  = threadIdx.x;
    const int lane = tid & 63;
    const int w    = tid >> 6;      // wave 0..11
    const int h    = w >> 1;        // head 0..5
    const int m    = w & 1;         // token half 0..1
    const int quad = lane >> 4;
    const int l16  = lane & 15;

    const int  srcA = ((lane & 16) << 1) | l16;   // ((quad&1)*2)*16 + l16
    const bool hiq  = (lane & 32) != 0;           // quad>>1

    int colb[6];
    #pragma unroll
    for (int t = 0; t < 6; ++t) colb[t] = (t >> 1) * 192 + h * 32 + (t & 1) * 16;

    // ---------------- phase 1: stage x (fp32 -> bf16), pad, mask bias -----
    const float* xb = x + (size_t)b * 9408;
    for (int i4 = tid; i4 < 2352; i4 += 768) {   // 9408 elems / 4
        int flat = i4 * 4;
        int n = flat / 192, c = flat % 192;      // 192 % 4 == 0: no row cross
        float4 v = *(const float4*)(const void*)&xb[flat];
        uint2 pk;
        pk.x = pkbf(v.x, v.y);
        pk.y = pkbf(v.z, v.w);
        *(uint2*)(void*)&region[n * 200 + c] = pk;
    }
    if (tid < 375) {                              // zero rows 49..63 (15*200)
        uint4 z = {0u, 0u, 0u, 0u};
        *(uint4*)(void*)&region[9800 + tid * 8] = z;
    }
    if (tid < 64)
        mbias[tid] = (tid < 49 && mask[b * 49 + tid] != 0) ? 0.0f : -1e30f;

    // preload kt=0 weight fragments (L2 latency hides under the barrier)
    short8 bw0[6];
    #pragma unroll
    for (int t = 0; t < 6; ++t)
        bw0[t] = *(const short8*)(const void*)
                 &wq[(size_t)(colb[t] + l16) * 32 + quad * 8];

    __syncthreads();   // B1: x + mbias visible

    // ---------------- phase 2: QKV GEMM for token tiles {2m, 2m+1} --------
    // t=0..3 (q,k) swapped: acc[t][i] = Y[token=(2m+i)*16+l16][colb[t]+quad*4+r]
    // t=4..5 (v) normal:    acc[t][i] = V[token=(2m+i)*16+quad*4+r][..+l16]
    f32x4 acc[6][2];
    #pragma unroll
    for (int t = 0; t < 6; ++t)
        #pragma unroll
        for (int i = 0; i < 2; ++i)
            acc[t][i] = (f32x4){0.f, 0.f, 0.f, 0.f};

    #pragma unroll
    for (int kt = 0; kt < 6; ++kt) {
        short8 af[2];
        #pragma unroll
        for (int i = 0; i < 2; ++i)
            af[i] = *(const short8*)(const void*)
                    &region[((2 * m + i) * 16 + l16) * 200 + kt * 32 + quad * 8];
        #pragma unroll
        for (int t = 0; t < 6; ++t) {
            short8 bw = (kt == 0) ? bw0[t]
                      : *(const short8*)(const void*)
                        &wq[(size_t)(kt * 576 + colb[t] + l16) * 32 + quad * 8];
            #pragma unroll
            for (int i = 0; i < 2; ++i) {
                if (t < 4)
                    acc[t][i] = __builtin_amdgcn_mfma_f32_16x16x32_bf16(
                                    bw, af[i], acc[t][i], 0, 0, 0);
                else
                    acc[t][i] = __builtin_amdgcn_mfma_f32_16x16x32_bf16(
                                    af[i], bw, acc[t][i], 0, 0, 0);
            }
        }
    }

    // bias + collapse (values bit-identical to v10's qf/kf/vf for these tiles)
    short8 qf[2];
    {
        f32x4 bq0 = *(const f32x4*)(const void*)&bqkv[colb[0] + quad * 4];
        f32x4 bq1 = *(const f32x4*)(const void*)&bqkv[colb[1] + quad * 4];
        f32x4 bk0 = *(const f32x4*)(const void*)&bqkv[colb[2] + quad * 4];
        f32x4 bk1 = *(const f32x4*)(const void*)&bqkv[colb[3] + quad * 4];
        #pragma unroll
        for (int i = 0; i < 2; ++i) {
            qf[i] = xpose(acc[0][i] + bq0, acc[1][i] + bq1, srcA, hiq);
            kfb[h][2 * m + i][lane]
                = xpose(acc[2][i] + bk0, acc[3][i] + bk1, srcA, hiq);
        }
        float bv0 = bqkv[colb[4] + l16];
        float bv1 = bqkv[colb[5] + l16];
        // this wave's two token tiles form exactly dual-pack pair j = m
        vfb[h][0][m][lane] = cvt8(addb(acc[4][0], bv0), addb(acc[4][1], bv0));
        vfb[h][1][m][lane] = cvt8(addb(acc[5][0], bv1), addb(acc[5][1], bv1));
    }

    __syncthreads();   // B2: kfb/vfb visible; x dead -> region becomes O_all

    // full-K fragments (verbatim re-read; bit-identical to v10's kf/vf)
    short8 kf[4], vf[2][2];
    #pragma unroll
    for (int mt = 0; mt < 4; ++mt) kf[mt] = kfb[h][mt][lane];
    #pragma unroll
    for (int t = 0; t < 2; ++t)
        #pragma unroll
        for (int j = 0; j < 2; ++j) vf[t][j] = vfb[h][t][j][lane];

    f32x4 mb4[4];
    #pragma unroll
    for (int mt = 0; mt < 4; ++mt)
        mb4[mt] = *(const f32x4*)(const void*)&mbias[mt * 16 + quad * 4];

    // ---------------- phase 4+5: own q-tiles {2m,2m+1}: S, softmax, O -----
    #pragma unroll
    for (int i = 0; i < 2; ++i) {
        const int nt = 2 * m + i;
        // sr[mt]: lane holds S[q=nt*16+l16][k=mt*16+quad*4+r]
        f32x4 sr[4];
        #pragma unroll
        for (int mt = 0; mt < 4; ++mt) {
            sr[mt] = (f32x4){0.f, 0.f, 0.f, 0.f};
            sr[mt] = __builtin_amdgcn_mfma_f32_16x16x32_bf16(
                         kf[mt], qf[i], sr[mt], 0, 0, 0);
        }
        float pm[4];
        #pragma unroll
        for (int mt = 0; mt < 4; ++mt) {
            #pragma unroll
            for (int r = 0; r < 4; ++r)
                sr[mt][r] = sr[mt][r] * SCALE + mb4[mt][r];
            pm[mt] = fmaxf(fmaxf(sr[mt][0], sr[mt][1]),
                           fmaxf(sr[mt][2], sr[mt][3]));
        }
        float mx = fmaxf(fmaxf(pm[0], pm[1]), fmaxf(pm[2], pm[3]));
        mx = fmaxf(mx, __shfl_xor(mx, 16));
        mx = fmaxf(mx, __shfl_xor(mx, 32));
        float ps[4];
        #pragma unroll
        for (int mt = 0; mt < 4; ++mt) {
            #pragma unroll
            for (int r = 0; r < 4; ++r)
                sr[mt][r] = __expf(sr[mt][r] - mx);
            ps[mt] = (sr[mt][0] + sr[mt][1]) + (sr[mt][2] + sr[mt][3]);
        }
        float sum = (ps[0] + ps[1]) + (ps[2] + ps[3]);
        sum += __shfl_xor(sum, 16);
        sum += __shfl_xor(sum, 32);
        float inv = 1.0f / sum;
        #pragma unroll
        for (int mt = 0; mt < 4; ++mt)
            #pragma unroll
            for (int r = 0; r < 4; ++r)
                sr[mt][r] *= inv;

        // pf[j]: P A-fragment, token pair (2j,2j+1) dual-packed
        short8 pf[2];
        pf[0] = cvt8(sr[0], sr[1]);
        pf[1] = cvt8(sr[2], sr[3]);

        // O slice (C-layout [q=nt*16+quad*4+r][d=t*16+l16])
        f32x4 on[2];
        #pragma unroll
        for (int t = 0; t < 2; ++t)
            on[t] = (f32x4){0.f, 0.f, 0.f, 0.f};
        #pragma unroll
        for (int j = 0; j < 2; ++j)
            #pragma unroll
            for (int t = 0; t < 2; ++t)
                on[t] = __builtin_amdgcn_mfma_f32_16x16x32_bf16(
                            pf[j], vf[t][j], on[t], 0, 0, 0);

        #pragma unroll
        for (int t = 0; t < 2; ++t)
            #pragma unroll
            for (int r = 0; r < 4; ++r)
                region[(nt * 16 + quad * 4 + r) * 200 + h * 32 + t * 16 + l16]
                    = f2bf(on[t][r]);
    }

    // preload projection-weight fragments (L2 latency under barrier)
    short8 bwp[6][2];
    #pragma unroll
    for (int kt = 0; kt < 6; ++kt)
        #pragma unroll
        for (int nt = 0; nt < 2; ++nt)
            bwp[kt][nt] = *(const short8*)(const void*)
                          &wpj[(size_t)(kt * 192 + h * 32 + nt * 16 + l16) * 32
                               + quad * 8];

    __syncthreads();   // B3: all heads' O visible

    // ---------------- phase 6: projection (own rows x own head cols) ------
    f32x4 po[2][2];    // [col tile nt][row tile i (= token tile 2m+i)]
    #pragma unroll
    for (int nt = 0; nt < 2; ++nt)
        #pragma unroll
        for (int i = 0; i < 2; ++i)
            po[nt][i] = (f32x4){0.f, 0.f, 0.f, 0.f};

    #pragma unroll
    for (int kt = 0; kt < 6; ++kt) {
        short8 ao[2];
        #pragma unroll
        for (int i = 0; i < 2; ++i)
            ao[i] = *(const short8*)(const void*)
                    &region[((2 * m + i) * 16 + l16) * 200 + kt * 32 + quad * 8];
        #pragma unroll
        for (int nt = 0; nt < 2; ++nt)
            #pragma unroll
            for (int i = 0; i < 2; ++i)
                po[nt][i] = __builtin_amdgcn_mfma_f32_16x16x32_bf16(
                                ao[i], bwp[kt][nt], po[nt][i], 0, 0, 0);
    }

    #pragma unroll
    for (int nt = 0; nt < 2; ++nt) {
        int col = h * 32 + nt * 16 + l16;
        float bv = bproj[col];
        #pragma unroll
        for (int i = 0; i < 2; ++i)
            #pragma unroll
            for (int r = 0; r < 4; ++r) {
                int row = (2 * m + i) * 16 + quad * 4 + r;
                if (row < 49)
                    out[(size_t)b * 9408 + row * 192 + col] = po[nt][i][r] + bv;
            }
    }
}

extern "C" void kernel_launch(void* const* d_in, const int* in_sizes, int n_in,
                              void* d_out, int out_size, void* d_ws, size_t ws_size,
                              hipStream_t stream) {
    const float* x      = (const float*)d_in[0];
    const int*   mask   = (const int*)d_in[1];
    const float* w_qkv  = (const float*)d_in[2];
    const float* b_qkv  = (const float*)d_in[3];
    const float* w_proj = (const float*)d_in[4];
    const float* b_proj = (const float*)d_in[5];
    float*       out    = (float*)d_out;

    unsigned short* wq_pack = (unsigned short*)d_ws;          // 110592 elems
    unsigned short* wp_pack = wq_pack + 110592;               //  36864 elems

    repack_kernel<<<(110592 + 36864 + 255) / 256, 256, 0, stream>>>(
        w_qkv, w_proj, wq_pack, wp_pack);
    win_attn_kernel<<<8192, 768, 0, stream>>>(x, mask, b_qkv, b_proj,
                                              wq_pack, wp_pack, out);
}